// Round 18
// baseline (487.292 us; speedup 1.0000x reference)
//
#include <hip/hip_runtime.h>

typedef __bf16 bf16x8 __attribute__((ext_vector_type(8)));
typedef __bf16 bf16x4 __attribute__((ext_vector_type(4)));
typedef float f32x4 __attribute__((ext_vector_type(4)));
typedef float f32x16 __attribute__((ext_vector_type(16)));

#define MFMA16(a,b,c) __builtin_amdgcn_mfma_f32_16x16x32_bf16((a),(b),(c),0,0,0)
#define MFMA32(a,b,c) __builtin_amdgcn_mfma_f32_32x32x16_bf16((a),(b),(c),0,0,0)
#define EXP2R(x) __builtin_amdgcn_exp2f(x)

#define BB   16
#define SEQ  1024
#define CD   768
#define NHD  12
#define HDD  64
#define HID  3072
#define MT   (BB*SEQ)   // 16384

__device__ __forceinline__ void gload16(const void* g, void* l) {
    __builtin_amdgcn_global_load_lds(
        (const __attribute__((address_space(1))) void*)g,
        (__attribute__((address_space(3))) void*)l, 16, 0, 0);
}

__device__ __forceinline__ unsigned pk2(float lo, float hi) {
    unsigned short a = __builtin_bit_cast(unsigned short, (__bf16)lo);
    unsigned short b = __builtin_bit_cast(unsigned short, (__bf16)hi);
    return (unsigned)a | ((unsigned)b << 16);
}

// branchless GELU (tanh form)
__device__ __forceinline__ float fast_gelu(float x) {
    float u = x * x * x;
    float y = fmaf(0.044715f, u, x);
    float e = EXP2R(-2.3022083f * y);
    return x * __builtin_amdgcn_rcpf(1.0f + e);
}

// ---------------- fused prep: 4 weight transposes + LN1 ----------------------
__device__ __forceinline__ void transpose_body(
    const float* __restrict__ W, __bf16* __restrict__ WT, int R, int C, int bid,
    float (*t)[33])
{
    int tc = C >> 5;
    int br = bid / tc, bc = bid % tc;
    int x = threadIdx.x & 31, y = threadIdx.x >> 5;
#pragma unroll
    for (int i = 0; i < 4; ++i)
        t[y + 8*i][x] = W[(size_t)(br*32 + y + 8*i)*C + bc*32 + x];
    __syncthreads();
#pragma unroll
    for (int i = 0; i < 4; ++i)
        WT[(size_t)(bc*32 + y + 8*i)*R + br*32 + x] = (__bf16)t[x][y + 8*i];
}

__device__ __forceinline__ void ln_body(
    const float* __restrict__ xin, const float* __restrict__ g,
    const float* __restrict__ bb, __bf16* out, int bid)
{
    int row = bid * 4 + ((int)threadIdx.x >> 6);
    int lane = threadIdx.x & 63;
    const float* xr = xin + (size_t)row * CD + lane * 4;
    float4 v0 = *(const float4*)(xr);
    float4 v1 = *(const float4*)(xr + 256);
    float4 v2 = *(const float4*)(xr + 512);
    float s = v0.x+v0.y+v0.z+v0.w + v1.x+v1.y+v1.z+v1.w + v2.x+v2.y+v2.z+v2.w;
#pragma unroll
    for (int off = 1; off < 64; off <<= 1) s += __shfl_xor(s, off);
    float mu = s * (1.0f/768.0f);
    float q =
        (v0.x-mu)*(v0.x-mu)+(v0.y-mu)*(v0.y-mu)+(v0.z-mu)*(v0.z-mu)+(v0.w-mu)*(v0.w-mu)+
        (v1.x-mu)*(v1.x-mu)+(v1.y-mu)*(v1.y-mu)+(v1.z-mu)*(v1.z-mu)+(v1.w-mu)*(v1.w-mu)+
        (v2.x-mu)*(v2.x-mu)+(v2.y-mu)*(v2.y-mu)+(v2.z-mu)*(v2.z-mu)+(v2.w-mu)*(v2.w-mu);
#pragma unroll
    for (int off = 1; off < 64; off <<= 1) q += __shfl_xor(q, off);
    float rstd = rsqrtf(q * (1.0f/768.0f) + 1e-5f);

    __bf16* orow = out + (size_t)row * CD + lane * 4;
#pragma unroll
    for (int p = 0; p < 3; ++p) {
        float4 xv = (p == 0) ? v0 : (p == 1) ? v1 : v2;
        float4 gv = *(const float4*)(g  + p*256 + lane*4);
        float4 bv = *(const float4*)(bb + p*256 + lane*4);
        bf16x4 ov;
        ov[0] = (__bf16)((xv.x-mu)*rstd*gv.x + bv.x);
        ov[1] = (__bf16)((xv.y-mu)*rstd*gv.y + bv.y);
        ov[2] = (__bf16)((xv.z-mu)*rstd*gv.z + bv.z);
        ov[3] = (__bf16)((xv.w-mu)*rstd*gv.w + bv.w);
        *(bf16x4*)(orow + p*256) = ov;
    }
}

__global__ __launch_bounds__(256)
void prep_kernel(const float* qkvw, const float* projw, const float* fc1w, const float* fc2w,
                 __bf16* wqkvT, __bf16* wprojT, __bf16* wfc1T, __bf16* wfc2T,
                 const float* x, const float* g1, const float* b1, __bf16* hbuf)
{
    __shared__ float t[32][33];
    int bid = blockIdx.x;
    if (bid < 1728) { transpose_body(qkvw,  wqkvT,  CD,  3*CD, bid, t); return; }
    bid -= 1728;
    if (bid < 576)  { transpose_body(projw, wprojT, CD,  CD,   bid, t); return; }
    bid -= 576;
    if (bid < 2304) { transpose_body(fc1w,  wfc1T,  CD,  HID,  bid, t); return; }
    bid -= 2304;
    if (bid < 2304) { transpose_body(fc2w,  wfc2T,  HID, CD,   bid, t); return; }
    bid -= 2304;
    ln_body(x, g1, b1, hbuf, bid);
}

__global__ __launch_bounds__(256)
void ln_kernel(const float* __restrict__ xin, const float* __restrict__ g,
               const float* __restrict__ bb, __bf16* out)
{
    ln_body(xin, g, bb, out, blockIdx.x);
}

// ---------------- GEMM 128x128, BK=32, packed A|B rows, 32 KB LDS -------------
// Same 2-phase schedule as the proven R15/R17 kernel; tile K-depth halved and
// A/B packed into shared 128-B LDS rows (A = chunks 0-3, B = chunks 4-7, same
// XOR involution on the 8-chunk domain). LDS 32 KB -> 4 blocks/CU: fc2/proj
// grids (768) become FULLY resident (zero scheduling tail) and 4 independent
// blocks cover each other's barrier drains.
template<int EPI>
__global__ __launch_bounds__(512)
void gemm_bt(const __bf16* __restrict__ A, const __bf16* __restrict__ BT,
             const float* __restrict__ bias,
             const float* res, float* outf,
             __bf16* __restrict__ outb,
             __bf16* __restrict__ qb, __bf16* __restrict__ kb, __bf16* __restrict__ vb,
             int M, int N, int K)
{
    __shared__ alignas(16) __bf16 ls[2][128*64];   // [2][128 rows][128 B] = 32 KB

    int nbn = N >> 7;
    int nwg = (M >> 7) * nbn;
    int bid = (int)blockIdx.x;
    int cpx = nwg >> 3;
    int sw = (bid & 7) * cpx + (bid >> 3);
    int bm = sw / nbn, bn = sw % nbn;
    int row0 = bm << 7, col0 = bn << 7;

    int tid = threadIdx.x;
    int lane = tid & 63, w = tid >> 6;       // w: 0..7
    int wr = w >> 2, wc = w & 3;             // 2 x 4 wave grid; wave tile 64x32
    int lr = lane & 15, lg = lane >> 4;      // lg: 0..3 (16B k-chunk)

    f32x4 acc[4][2] = {};

    // per-thread staging source: dest byte s -> row s>>7, phys chunk (s>>4)&7,
    // logical chunk c = phys ^ (row&7); c<4 -> A k-chunk c, else B k-chunk c-4.
    const __bf16* sbase0;
    const __bf16* sbase1;
    {
        int s0 = tid * 16;
        int r0 = s0 >> 7, c0 = ((s0 >> 4) & 7) ^ (r0 & 7);
        sbase0 = (c0 < 4) ? (A  + (size_t)(row0 + r0)*K + c0*8)
                          : (BT + (size_t)(col0 + r0)*K + (c0 - 4)*8);
        int s1 = s0 + 8192;
        int r1 = s1 >> 7, c1 = ((s1 >> 4) & 7) ^ (r1 & 7);
        sbase1 = (c1 < 4) ? (A  + (size_t)(row0 + r1)*K + c1*8)
                          : (BT + (size_t)(col0 + r1)*K + (c1 - 4)*8);
    }

    auto stage = [&](int buf, int ktE) {
        char* d = (char*)ls + buf*16384 + w*1024;   // wave-uniform; HW adds lane*16
        gload16(sbase0 + ktE, d);
        gload16(sbase1 + ktE, d + 8192);
    };

    int nkt = K >> 5;
    stage(0, 0);
    __syncthreads();                    // buf0 ready
    int cur = 0;

    for (int kt = 0; kt < nkt; ++kt) {
        if (kt + 1 < nkt) stage(cur ^ 1, (kt + 1) << 5);   // prefetch under compute

        const char* lb = (const char*)ls + cur*16384;
        bf16x8 af[4], bfv[2];
#pragma unroll
        for (int m = 0; m < 4; ++m) {
            int row = wr*64 + m*16 + lr;
            af[m] = *(const bf16x8*)(lb + row*128 + ((lg ^ (row & 7)) << 4));
        }
#pragma unroll
        for (int n = 0; n < 2; ++n) {
            int row = wc*32 + n*16 + lr;
            bfv[n] = *(const bf16x8*)(lb + row*128 + (((lg ^ 4) ^ (row & 7)) << 4));
        }
#pragma unroll
        for (int m = 0; m < 4; ++m)
#pragma unroll
            for (int n = 0; n < 2; ++n)
                acc[m][n] = MFMA16(af[m], bfv[n], acc[m][n]);

        __syncthreads();                // drains: next-tile loads + my LDS reads
        cur ^= 1;
    }

    int rbase = row0 + wr*64 + lg*4;
    int cbase = col0 + wc*32 + lr;
#pragma unroll
    for (int n = 0; n < 2; ++n) {
        int col = cbase + n*16;
        float bv = bias[col];
        if constexpr (EPI == 0) {
            int which = col / CD;
            int c2 = col - which * CD;
            int head = c2 >> 6, d = c2 & 63;
#pragma unroll
            for (int m = 0; m < 4; ++m) {
                int r0 = rbase + m*16;
                int b = r0 >> 10, nn = r0 & 1023;
                if (which == 2) {
                    bf16x4 pv;
#pragma unroll
                    for (int j = 0; j < 4; ++j) pv[j] = (__bf16)(acc[m][n][j] + bv);
                    *(bf16x4*)&vb[(((size_t)b*NHD + head)*HDD + d)*SEQ + nn] = pv;
                } else {
                    __bf16* dst = (which == 0) ? qb : kb;
#pragma unroll
                    for (int j = 0; j < 4; ++j)
                        dst[(((size_t)b*NHD + head)*SEQ + nn + j)*HDD + d] =
                            (__bf16)(acc[m][n][j] + bv);
                }
            }
        } else {
#pragma unroll
            for (int m = 0; m < 4; ++m) {
                int rr = rbase + m*16;
#pragma unroll
                for (int j = 0; j < 4; ++j) {
                    float val = acc[m][n][j] + bv;
                    int r = rr + j;
                    if constexpr (EPI == 1) {
                        outf[(size_t)r*N + col] = res[(size_t)r*N + col] + val;
                    } else {
                        outb[(size_t)r*N + col] = (__bf16)fast_gelu(val);
                    }
                }
            }
        }
    }
}

// ---------------- flash attention: swapped-QK^T, fixed-max softmax ------------
// 8 waves / 512 threads / 256 q-rows per block (R17-verified).
__global__ __launch_bounds__(512)
void attn_kernel(const __bf16* __restrict__ q, const __bf16* __restrict__ k,
                 const __bf16* __restrict__ vT, __bf16* __restrict__ o)
{
    __shared__ alignas(16) __bf16 kls[2][64*64];
    __shared__ alignas(16) __bf16 vls[2][64*64];

    int bid = blockIdx.x;                // 768 blocks
    int x = bid & 7, u = bid >> 3;
    int bh = x*24 + (u >> 2);
    int qt = u & 3;
    int b = bh / NHD, hh = bh % NHD;
    int tid = threadIdx.x, lane = tid & 63, w = tid >> 6;
    int lq = lane & 31, h = lane >> 5;

    int qg = qt*256 + w*32 + lq;
    const __bf16* qp = q + ((size_t)bh*SEQ + qg)*HDD + h*8;
    bf16x8 qf[4];
#pragma unroll
    for (int s = 0; s < 4; ++s) qf[s] = *(const bf16x8*)(qp + s*16);

    const __bf16* kbase = k  + (size_t)bh*SEQ*HDD;
    const __bf16* vbase = vT + (size_t)bh*HDD*SEQ;

    int srow = tid >> 3;
    int scol = ((tid & 7) ^ (srow & 7)) * 8;

    auto stage = [&](int buf, int kv) {
        char* kl = (char*)kls + buf*8192 + w*1024;
        char* vl = (char*)vls + buf*8192 + w*1024;
        gload16(kbase + (size_t)(kv + srow)*HDD + scol, kl);
        gload16(vbase + (size_t)srow*SEQ + kv + scol, vl);
    };

    const float SCL2 = 0.125f * 1.44269504f;
    const float NB   = -12.0f * SCL2;
    float lrun = 0.f;
    f32x16 oa0 = {}, oa1 = {};

    stage(0, 0);
    __syncthreads();
    int cur = 0;
    int rswz = (lq & 7) << 4;

    for (int kt = 0; kt < SEQ/64; ++kt) {
        if (kt + 1 < SEQ/64) stage(cur ^ 1, (kt + 1)*64);

        const char* kc = (const char*)kls + cur*8192;
        const char* vc = (const char*)vls + cur*8192;

        bf16x8 ka0[4], ka1[4];
#pragma unroll
        for (int s = 0; s < 4; ++s) {
            int bc = (h*16 + s*32) ^ rswz;
            ka0[s] = *(const bf16x8*)(kc + lq*128 + bc);
            ka1[s] = *(const bf16x8*)(kc + (lq + 32)*128 + bc);
        }
        bf16x8 vf0[4], vf1[4];
#pragma unroll
        for (int g = 0; g < 4; ++g) {
            int bc = (h*16 + g*32) ^ rswz;
            vf0[g] = *(const bf16x8*)(vc + lq*128 + bc);
            vf1[g] = *(const bf16x8*)(vc + (lq + 32)*128 + bc);
        }

        f32x16 s0 = {}, s1 = {};
        __builtin_amdgcn_s_setprio(1);
#pragma unroll
        for (int s = 0; s < 4; ++s) {
            s0 = MFMA32(ka0[s], qf[s], s0);
            s1 = MFMA32(ka1[s], qf[s], s1);
        }
        __builtin_amdgcn_s_setprio(0);

#pragma unroll
        for (int i = 0; i < 16; ++i) s0[i] = EXP2R(fmaf(s0[i], SCL2, NB));
#pragma unroll
        for (int i = 0; i < 16; ++i) s1[i] = EXP2R(fmaf(s1[i], SCL2, NB));
        float a8[8];
#pragma unroll
        for (int i = 0; i < 8; ++i)
            a8[i] = (s0[i] + s0[i + 8]) + (s1[i] + s1[i + 8]);
        float s4a = (a8[0] + a8[1]) + (a8[2] + a8[3]);
        float s4b = (a8[4] + a8[5]) + (a8[6] + a8[7]);
        lrun += s4a + s4b;

#pragma unroll
        for (int t = 0; t < 2; ++t) {
            const f32x16& sp = t ? s1 : s0;
            unsigned d0 = pk2(sp[ 0], sp[ 1]);
            unsigned d1 = pk2(sp[ 2], sp[ 3]);
            unsigned d2 = pk2(sp[ 4], sp[ 5]);
            unsigned d3 = pk2(sp[ 6], sp[ 7]);
            unsigned d4 = pk2(sp[ 8], sp[ 9]);
            unsigned d5 = pk2(sp[10], sp[11]);
            unsigned d6 = pk2(sp[12], sp[13]);
            unsigned d7 = pk2(sp[14], sp[15]);
            unsigned pd0 = __shfl_xor(d0, 32), pd1 = __shfl_xor(d1, 32);
            unsigned pd2 = __shfl_xor(d2, 32), pd3 = __shfl_xor(d3, 32);
            unsigned pd4 = __shfl_xor(d4, 32), pd5 = __shfl_xor(d5, 32);
            unsigned pd6 = __shfl_xor(d6, 32), pd7 = __shfl_xor(d7, 32);
            union { unsigned u[4]; bf16x8 v; } f0, f1;
            f0.u[0] = h ? pd2 : d0;
            f0.u[1] = h ? pd3 : d1;
            f0.u[2] = h ? d2 : pd0;
            f0.u[3] = h ? d3 : pd1;
            f1.u[0] = h ? pd6 : d4;
            f1.u[1] = h ? pd7 : d5;
            f1.u[2] = h ? d6 : pd4;
            f1.u[3] = h ? d7 : pd5;
            __builtin_amdgcn_s_setprio(1);
            oa0 = MFMA32(vf0[t*2 + 0], f0.v, oa0);
            oa1 = MFMA32(vf1[t*2 + 0], f0.v, oa1);
            oa0 = MFMA32(vf0[t*2 + 1], f1.v, oa0);
            oa1 = MFMA32(vf1[t*2 + 1], f1.v, oa1);
            __builtin_amdgcn_s_setprio(0);
        }

        __syncthreads();
        cur ^= 1;
    }

    lrun += __shfl_xor(lrun, 32);
    float inv = __builtin_amdgcn_rcpf(lrun);
    oa0 = oa0 * inv;
    oa1 = oa1 * inv;
    __bf16* orow = o + ((size_t)b*SEQ + qg)*CD + hh*HDD;
#pragma unroll
    for (int dt = 0; dt < 2; ++dt) {
        f32x16 oa = dt ? oa1 : oa0;
        unsigned d0 = pk2(oa[ 0], oa[ 1]);
        unsigned d1 = pk2(oa[ 2], oa[ 3]);
        unsigned d2 = pk2(oa[ 4], oa[ 5]);
        unsigned d3 = pk2(oa[ 6], oa[ 7]);
        unsigned d4 = pk2(oa[ 8], oa[ 9]);
        unsigned d5 = pk2(oa[10], oa[11]);
        unsigned d6 = pk2(oa[12], oa[13]);
        unsigned d7 = pk2(oa[14], oa[15]);
        unsigned pd0 = __shfl_xor(d0, 32), pd1 = __shfl_xor(d1, 32);
        unsigned pd2 = __shfl_xor(d2, 32), pd3 = __shfl_xor(d3, 32);
        unsigned pd4 = __shfl_xor(d4, 32), pd5 = __shfl_xor(d5, 32);
        unsigned pd6 = __shfl_xor(d6, 32), pd7 = __shfl_xor(d7, 32);
        union { unsigned u[4]; bf16x8 v; } g0, g1;
        g0.u[0] = h ? pd2 : d0;
        g0.u[1] = h ? pd3 : d1;
        g0.u[2] = h ? d2 : pd0;
        g0.u[3] = h ? d3 : pd1;
        g1.u[0] = h ? pd6 : d4;
        g1.u[1] = h ? pd7 : d5;
        g1.u[2] = h ? d6 : pd4;
        g1.u[3] = h ? d7 : pd5;
        *(bf16x8*)(orow + dt*32 +  0 + h*8) = g0.v;
        *(bf16x8*)(orow + dt*32 + 16 + h*8) = g1.v;
    }
}

// ------------------------------- launch ---------------------------------------
extern "C" void kernel_launch(void* const* d_in, const int* in_sizes, int n_in,
                              void* d_out, int out_size, void* d_ws, size_t ws_size,
                              hipStream_t stream)
{
    const float* x     = (const float*)d_in[0];
    const float* ln1g  = (const float*)d_in[1];
    const float* ln1b  = (const float*)d_in[2];
    const float* qkvw  = (const float*)d_in[3];
    const float* qkvb  = (const float*)d_in[4];
    const float* projw = (const float*)d_in[5];
    const float* projb = (const float*)d_in[6];
    const float* ln2g  = (const float*)d_in[7];
    const float* ln2b  = (const float*)d_in[8];
    const float* fc1w  = (const float*)d_in[9];
    const float* fc1b  = (const float*)d_in[10];
    const float* fc2w  = (const float*)d_in[11];
    const float* fc2b  = (const float*)d_in[12];
    float* out = (float*)d_out;

    char* p = (char*)d_ws;
    auto alloc = [&](size_t bytes) { char* r = p; p += (bytes + 255) & ~(size_t)255; return r; };
    __bf16* wqkvT  = (__bf16*)alloc((size_t)3*CD*CD*2);
    __bf16* wprojT = (__bf16*)alloc((size_t)CD*CD*2);
    __bf16* wfc1T  = (__bf16*)alloc((size_t)HID*CD*2);
    __bf16* wfc2T  = (__bf16*)alloc((size_t)CD*HID*2);
    __bf16* hbuf   = (__bf16*)alloc((size_t)MT*CD*2);
    __bf16* qbuf   = (__bf16*)alloc((size_t)BB*NHD*SEQ*HDD*2);
    __bf16* kbuf   = (__bf16*)alloc((size_t)BB*NHD*SEQ*HDD*2);
    __bf16* vtbuf  = (__bf16*)alloc((size_t)BB*NHD*SEQ*HDD*2);
    (void)alloc((size_t)BB*NHD*SEQ*HDD*2);  // pad so hhbuf (=qbuf) spans 96 MB
    __bf16* hhbuf  = qbuf;                  // reuse for the [MT][3072] MLP act

    prep_kernel<<<1728 + 576 + 2304 + 2304 + MT/4, 256, 0, stream>>>(
        qkvw, projw, fc1w, fc2w, wqkvT, wprojT, wfc1T, wfc2T, x, ln1g, ln1b, hbuf);

    gemm_bt<0><<<(MT/128)*(3*CD/128), 512, 0, stream>>>(
        hbuf, wqkvT, qkvb, nullptr, nullptr, nullptr, qbuf, kbuf, vtbuf, MT, 3*CD, CD);

    attn_kernel<<<BB*NHD*4, 512, 0, stream>>>(qbuf, kbuf, vtbuf, hbuf);

    gemm_bt<1><<<(MT/128)*(CD/128), 512, 0, stream>>>(
        hbuf, wprojT, projb, x, out, nullptr, nullptr, nullptr, nullptr, MT, CD, CD);

    ln_kernel<<<MT/4, 256, 0, stream>>>(out, ln2g, ln2b, hbuf);

    gemm_bt<2><<<(MT/128)*(HID/128), 512, 0, stream>>>(
        hbuf, wfc1T, fc1b, nullptr, nullptr, hhbuf, nullptr, nullptr, nullptr, MT, HID, CD);

    gemm_bt<1><<<(MT/128)*(CD/128), 512, 0, stream>>>(
        hhbuf, wfc2T, fc2b, out, out, nullptr, nullptr, nullptr, nullptr, MT, CD, HID);
}

// Round 19
// 452.110 us; speedup vs baseline: 1.0778x; 1.0778x over previous
//
#include <hip/hip_runtime.h>

typedef __bf16 bf16x8 __attribute__((ext_vector_type(8)));
typedef __bf16 bf16x4 __attribute__((ext_vector_type(4)));
typedef float f32x4 __attribute__((ext_vector_type(4)));
typedef float f32x16 __attribute__((ext_vector_type(16)));

#define MFMA16(a,b,c) __builtin_amdgcn_mfma_f32_16x16x32_bf16((a),(b),(c),0,0,0)
#define MFMA32(a,b,c) __builtin_amdgcn_mfma_f32_32x32x16_bf16((a),(b),(c),0,0,0)
#define EXP2R(x) __builtin_amdgcn_exp2f(x)

#define BB   16
#define SEQ  1024
#define CD   768
#define NHD  12
#define HDD  64
#define HID  3072
#define MT   (BB*SEQ)   // 16384

__device__ __forceinline__ void gload16(const void* g, void* l) {
    __builtin_amdgcn_global_load_lds(
        (const __attribute__((address_space(1))) void*)g,
        (__attribute__((address_space(3))) void*)l, 16, 0, 0);
}

__device__ __forceinline__ unsigned pk2(float lo, float hi) {
    unsigned short a = __builtin_bit_cast(unsigned short, (__bf16)lo);
    unsigned short b = __builtin_bit_cast(unsigned short, (__bf16)hi);
    return (unsigned)a | ((unsigned)b << 16);
}

// branchless GELU (tanh form)
__device__ __forceinline__ float fast_gelu(float x) {
    float u = x * x * x;
    float y = fmaf(0.044715f, u, x);
    float e = EXP2R(-2.3022083f * y);
    return x * __builtin_amdgcn_rcpf(1.0f + e);
}

// ---------------- fused prep: 4 weight transposes + LN1 ----------------------
__device__ __forceinline__ void transpose_body(
    const float* __restrict__ W, __bf16* __restrict__ WT, int R, int C, int bid,
    float (*t)[33])
{
    int tc = C >> 5;
    int br = bid / tc, bc = bid % tc;
    int x = threadIdx.x & 31, y = threadIdx.x >> 5;
#pragma unroll
    for (int i = 0; i < 4; ++i)
        t[y + 8*i][x] = W[(size_t)(br*32 + y + 8*i)*C + bc*32 + x];
    __syncthreads();
#pragma unroll
    for (int i = 0; i < 4; ++i)
        WT[(size_t)(bc*32 + y + 8*i)*R + br*32 + x] = (__bf16)t[x][y + 8*i];
}

__device__ __forceinline__ void ln_body(
    const float* __restrict__ xin, const float* __restrict__ g,
    const float* __restrict__ bb, __bf16* out, int bid)
{
    int row = bid * 4 + ((int)threadIdx.x >> 6);
    int lane = threadIdx.x & 63;
    const float* xr = xin + (size_t)row * CD + lane * 4;
    float4 v0 = *(const float4*)(xr);
    float4 v1 = *(const float4*)(xr + 256);
    float4 v2 = *(const float4*)(xr + 512);
    float s = v0.x+v0.y+v0.z+v0.w + v1.x+v1.y+v1.z+v1.w + v2.x+v2.y+v2.z+v2.w;
#pragma unroll
    for (int off = 1; off < 64; off <<= 1) s += __shfl_xor(s, off);
    float mu = s * (1.0f/768.0f);
    float q =
        (v0.x-mu)*(v0.x-mu)+(v0.y-mu)*(v0.y-mu)+(v0.z-mu)*(v0.z-mu)+(v0.w-mu)*(v0.w-mu)+
        (v1.x-mu)*(v1.x-mu)+(v1.y-mu)*(v1.y-mu)+(v1.z-mu)*(v1.z-mu)+(v1.w-mu)*(v1.w-mu)+
        (v2.x-mu)*(v2.x-mu)+(v2.y-mu)*(v2.y-mu)+(v2.z-mu)*(v2.z-mu)+(v2.w-mu)*(v2.w-mu);
#pragma unroll
    for (int off = 1; off < 64; off <<= 1) q += __shfl_xor(q, off);
    float rstd = rsqrtf(q * (1.0f/768.0f) + 1e-5f);

    __bf16* orow = out + (size_t)row * CD + lane * 4;
#pragma unroll
    for (int p = 0; p < 3; ++p) {
        float4 xv = (p == 0) ? v0 : (p == 1) ? v1 : v2;
        float4 gv = *(const float4*)(g  + p*256 + lane*4);
        float4 bv = *(const float4*)(bb + p*256 + lane*4);
        bf16x4 ov;
        ov[0] = (__bf16)((xv.x-mu)*rstd*gv.x + bv.x);
        ov[1] = (__bf16)((xv.y-mu)*rstd*gv.y + bv.y);
        ov[2] = (__bf16)((xv.z-mu)*rstd*gv.z + bv.z);
        ov[3] = (__bf16)((xv.w-mu)*rstd*gv.w + bv.w);
        *(bf16x4*)(orow + p*256) = ov;
    }
}

__global__ __launch_bounds__(256)
void prep_kernel(const float* qkvw, const float* projw, const float* fc1w, const float* fc2w,
                 __bf16* wqkvT, __bf16* wprojT, __bf16* wfc1T, __bf16* wfc2T,
                 const float* x, const float* g1, const float* b1, __bf16* hbuf)
{
    __shared__ float t[32][33];
    int bid = blockIdx.x;
    if (bid < 1728) { transpose_body(qkvw,  wqkvT,  CD,  3*CD, bid, t); return; }
    bid -= 1728;
    if (bid < 576)  { transpose_body(projw, wprojT, CD,  CD,   bid, t); return; }
    bid -= 576;
    if (bid < 2304) { transpose_body(fc1w,  wfc1T,  CD,  HID,  bid, t); return; }
    bid -= 2304;
    if (bid < 2304) { transpose_body(fc2w,  wfc2T,  HID, CD,   bid, t); return; }
    bid -= 2304;
    ln_body(x, g1, b1, hbuf, bid);
}

__global__ __launch_bounds__(256)
void ln_kernel(const float* __restrict__ xin, const float* __restrict__ g,
               const float* __restrict__ bb, __bf16* out)
{
    ln_body(xin, g, bb, out, blockIdx.x);
}

// ---------------- GEMM 128x128: R15-proven 2-phase dbuf, 8 waves --------------
// stage(next) issued before compute(cur); single __syncthreads per iter.
// Wave grid 2(M)x4(N): per-wave tile 64x32, acc[4][2].
template<int EPI>
__global__ __launch_bounds__(512)
void gemm_bt(const __bf16* __restrict__ A, const __bf16* __restrict__ BT,
             const float* __restrict__ bias,
             const float* res, float* outf,
             __bf16* __restrict__ outb,
             __bf16* __restrict__ qb, __bf16* __restrict__ kb, __bf16* __restrict__ vb,
             int M, int N, int K)
{
    __shared__ alignas(16) __bf16 lsA[2][128*64];
    __shared__ alignas(16) __bf16 lsB[2][128*64];

    int nbn = N >> 7;
    int nwg = (M >> 7) * nbn;
    int bid = (int)blockIdx.x;
    int cpx = nwg >> 3;
    int sw = (bid & 7) * cpx + (bid >> 3);
    int bm = sw / nbn, bn = sw % nbn;
    int row0 = bm << 7, col0 = bn << 7;

    int tid = threadIdx.x;
    int lane = tid & 63, w = tid >> 6;       // w: 0..7
    int wr = w >> 2, wc = w & 3;             // 2 x 4 wave grid
    int lr = lane & 15, lg = lane >> 4;

    f32x4 acc[4][2] = {};
    int swz = (lr & 7) << 4;

    auto stage = [&](int buf, int ktE) {
#pragma unroll
        for (int i = 0; i < 2; ++i) {
            int s = tid*16 + (i << 13);           // linear byte 0..16383
            int r = s >> 7;                       // 128B rows
            int ch = ((s >> 4) & 7) ^ (r & 7);    // inverse-swizzled source chunk
            gload16(A  + (size_t)(row0 + r)*K + (ktE + ch*8),
                    (char*)lsA + buf*16384 + w*1024 + (i << 13));
            gload16(BT + (size_t)(col0 + r)*K + (ktE + ch*8),
                    (char*)lsB + buf*16384 + w*1024 + (i << 13));
        }
    };

    int nkt = K >> 6;
    stage(0, 0);
    __syncthreads();                    // buf0 ready
    int cur = 0;

    for (int kt = 0; kt < nkt; ++kt) {
        if (kt + 1 < nkt) stage(cur ^ 1, (kt + 1) << 6);   // prefetch under compute

        const char* lA = (const char*)lsA + cur*16384;
        const char* lB = (const char*)lsB + cur*16384;
#pragma unroll
        for (int ks = 0; ks < 2; ++ks) {
            int cb = (ks*64 + lg*16) ^ swz;
            bf16x8 af[4], bfv[2];
#pragma unroll
            for (int m = 0; m < 4; ++m)
                af[m] = *(const bf16x8*)(lA + (wr*64 + m*16 + lr)*128 + cb);
#pragma unroll
            for (int n = 0; n < 2; ++n)
                bfv[n] = *(const bf16x8*)(lB + (wc*32 + n*16 + lr)*128 + cb);
#pragma unroll
            for (int m = 0; m < 4; ++m)
#pragma unroll
                for (int n = 0; n < 2; ++n)
                    acc[m][n] = MFMA16(af[m], bfv[n], acc[m][n]);
        }
        __syncthreads();                // drains: next-tile loads + my LDS reads
        cur ^= 1;
    }

    int rbase = row0 + wr*64 + lg*4;
    int cbase = col0 + wc*32 + lr;
#pragma unroll
    for (int n = 0; n < 2; ++n) {
        int col = cbase + n*16;
        float bv = bias[col];
        if constexpr (EPI == 0) {
            int which = col / CD;
            int c2 = col - which * CD;
            int head = c2 >> 6, d = c2 & 63;
#pragma unroll
            for (int m = 0; m < 4; ++m) {
                int r0 = rbase + m*16;
                int b = r0 >> 10, nn = r0 & 1023;
                if (which == 2) {
                    bf16x4 pv;
#pragma unroll
                    for (int j = 0; j < 4; ++j) pv[j] = (__bf16)(acc[m][n][j] + bv);
                    *(bf16x4*)&vb[(((size_t)b*NHD + head)*HDD + d)*SEQ + nn] = pv;
                } else {
                    __bf16* dst = (which == 0) ? qb : kb;
#pragma unroll
                    for (int j = 0; j < 4; ++j)
                        dst[(((size_t)b*NHD + head)*SEQ + nn + j)*HDD + d] =
                            (__bf16)(acc[m][n][j] + bv);
                }
            }
        } else {
#pragma unroll
            for (int m = 0; m < 4; ++m) {
                int rr = rbase + m*16;
#pragma unroll
                for (int j = 0; j < 4; ++j) {
                    float val = acc[m][n][j] + bv;
                    int r = rr + j;
                    if constexpr (EPI == 1) {
                        outf[(size_t)r*N + col] = res[(size_t)r*N + col] + val;
                    } else {
                        outb[(size_t)r*N + col] = (__bf16)fast_gelu(val);
                    }
                }
            }
        }
    }
}

// ---------------- flash attention: swapped-QK^T, fixed-max softmax ------------
// 8 waves / 512 threads / 256 q-rows per block: each staged 64-KV tile serves
// 2x the q-rows (half the K/V traffic), occupancy 32 waves/CU.
__global__ __launch_bounds__(512)
void attn_kernel(const __bf16* __restrict__ q, const __bf16* __restrict__ k,
                 const __bf16* __restrict__ vT, __bf16* __restrict__ o)
{
    __shared__ alignas(16) __bf16 kls[2][64*64];
    __shared__ alignas(16) __bf16 vls[2][64*64];

    int bid = blockIdx.x;                // 768 blocks
    int x = bid & 7, u = bid >> 3;       // XCD x runs u = 0,1,2,... in order
    int bh = x*24 + (u >> 2);            // 4 consecutive blocks share one bh
    int qt = u & 3;                      // q-tile of 256 rows
    int b = bh / NHD, hh = bh % NHD;
    int tid = threadIdx.x, lane = tid & 63, w = tid >> 6;   // w: 0..7
    int lq = lane & 31, h = lane >> 5;

    int qg = qt*256 + w*32 + lq;
    const __bf16* qp = q + ((size_t)bh*SEQ + qg)*HDD + h*8;
    bf16x8 qf[4];
#pragma unroll
    for (int s = 0; s < 4; ++s) qf[s] = *(const bf16x8*)(qp + s*16);

    const __bf16* kbase = k  + (size_t)bh*SEQ*HDD;
    const __bf16* vbase = vT + (size_t)bh*HDD*SEQ;

    // 512 threads cover the 8 KB tile in ONE round: byte s = tid*16,
    // row = tid>>3, chunk = tid&7 (inverse-swizzled source, linear dest).
    int srow = tid >> 3;                         // 0..63
    int scol = ((tid & 7) ^ (srow & 7)) * 8;

    auto stage = [&](int buf, int kv) {
        char* kl = (char*)kls + buf*8192 + w*1024;   // wave-uniform; HW adds lane*16
        char* vl = (char*)vls + buf*8192 + w*1024;
        gload16(kbase + (size_t)(kv + srow)*HDD + scol, kl);
        gload16(vbase + (size_t)srow*SEQ + kv + scol, vl);
    };

    const float SCL2 = 0.125f * 1.44269504f;
    const float NB   = -12.0f * SCL2;
    float lrun = 0.f;
    f32x16 oa0 = {}, oa1 = {};

    stage(0, 0);
    __syncthreads();
    int cur = 0;
    int rswz = (lq & 7) << 4;

    for (int kt = 0; kt < SEQ/64; ++kt) {
        if (kt + 1 < SEQ/64) stage(cur ^ 1, (kt + 1)*64);

        const char* kc = (const char*)kls + cur*8192;
        const char* vc = (const char*)vls + cur*8192;

        bf16x8 ka0[4], ka1[4];
#pragma unroll
        for (int s = 0; s < 4; ++s) {
            int bc = (h*16 + s*32) ^ rswz;
            ka0[s] = *(const bf16x8*)(kc + lq*128 + bc);
            ka1[s] = *(const bf16x8*)(kc + (lq + 32)*128 + bc);
        }
        bf16x8 vf0[4], vf1[4];
#pragma unroll
        for (int g = 0; g < 4; ++g) {
            int bc = (h*16 + g*32) ^ rswz;
            vf0[g] = *(const bf16x8*)(vc + lq*128 + bc);
            vf1[g] = *(const bf16x8*)(vc + (lq + 32)*128 + bc);
        }

        f32x16 s0 = {}, s1 = {};
        __builtin_amdgcn_s_setprio(1);
#pragma unroll
        for (int s = 0; s < 4; ++s) {
            s0 = MFMA32(ka0[s], qf[s], s0);
            s1 = MFMA32(ka1[s], qf[s], s1);
        }
        __builtin_amdgcn_s_setprio(0);

        // ---- fixed-max softmax: P = exp((S-12)*0.125) ----
#pragma unroll
        for (int i = 0; i < 16; ++i) s0[i] = EXP2R(fmaf(s0[i], SCL2, NB));
#pragma unroll
        for (int i = 0; i < 16; ++i) s1[i] = EXP2R(fmaf(s1[i], SCL2, NB));
        float a8[8];
#pragma unroll
        for (int i = 0; i < 8; ++i)
            a8[i] = (s0[i] + s0[i + 8]) + (s1[i] + s1[i + 8]);
        float s4a = (a8[0] + a8[1]) + (a8[2] + a8[3]);
        float s4b = (a8[4] + a8[5]) + (a8[6] + a8[7]);
        lrun += s4a + s4b;

        // ---- pack P^T D-frags -> B-frags ----
#pragma unroll
        for (int t = 0; t < 2; ++t) {
            const f32x16& sp = t ? s1 : s0;
            unsigned d0 = pk2(sp[ 0], sp[ 1]);
            unsigned d1 = pk2(sp[ 2], sp[ 3]);
            unsigned d2 = pk2(sp[ 4], sp[ 5]);
            unsigned d3 = pk2(sp[ 6], sp[ 7]);
            unsigned d4 = pk2(sp[ 8], sp[ 9]);
            unsigned d5 = pk2(sp[10], sp[11]);
            unsigned d6 = pk2(sp[12], sp[13]);
            unsigned d7 = pk2(sp[14], sp[15]);
            unsigned pd0 = __shfl_xor(d0, 32), pd1 = __shfl_xor(d1, 32);
            unsigned pd2 = __shfl_xor(d2, 32), pd3 = __shfl_xor(d3, 32);
            unsigned pd4 = __shfl_xor(d4, 32), pd5 = __shfl_xor(d5, 32);
            unsigned pd6 = __shfl_xor(d6, 32), pd7 = __shfl_xor(d7, 32);
            union { unsigned u[4]; bf16x8 v; } f0, f1;
            f0.u[0] = h ? pd2 : d0;
            f0.u[1] = h ? pd3 : d1;
            f0.u[2] = h ? d2 : pd0;
            f0.u[3] = h ? d3 : pd1;
            f1.u[0] = h ? pd6 : d4;
            f1.u[1] = h ? pd7 : d5;
            f1.u[2] = h ? d6 : pd4;
            f1.u[3] = h ? d7 : pd5;
            __builtin_amdgcn_s_setprio(1);
            oa0 = MFMA32(vf0[t*2 + 0], f0.v, oa0);
            oa1 = MFMA32(vf1[t*2 + 0], f0.v, oa1);
            oa0 = MFMA32(vf0[t*2 + 1], f1.v, oa0);
            oa1 = MFMA32(vf1[t*2 + 1], f1.v, oa1);
            __builtin_amdgcn_s_setprio(0);
        }

        __syncthreads();
        cur ^= 1;
    }

    lrun += __shfl_xor(lrun, 32);
    float inv = __builtin_amdgcn_rcpf(lrun);
    oa0 = oa0 * inv;
    oa1 = oa1 * inv;
    __bf16* orow = o + ((size_t)b*SEQ + qg)*CD + hh*HDD;
#pragma unroll
    for (int dt = 0; dt < 2; ++dt) {
        f32x16 oa = dt ? oa1 : oa0;
        unsigned d0 = pk2(oa[ 0], oa[ 1]);
        unsigned d1 = pk2(oa[ 2], oa[ 3]);
        unsigned d2 = pk2(oa[ 4], oa[ 5]);
        unsigned d3 = pk2(oa[ 6], oa[ 7]);
        unsigned d4 = pk2(oa[ 8], oa[ 9]);
        unsigned d5 = pk2(oa[10], oa[11]);
        unsigned d6 = pk2(oa[12], oa[13]);
        unsigned d7 = pk2(oa[14], oa[15]);
        unsigned pd0 = __shfl_xor(d0, 32), pd1 = __shfl_xor(d1, 32);
        unsigned pd2 = __shfl_xor(d2, 32), pd3 = __shfl_xor(d3, 32);
        unsigned pd4 = __shfl_xor(d4, 32), pd5 = __shfl_xor(d5, 32);
        unsigned pd6 = __shfl_xor(d6, 32), pd7 = __shfl_xor(d7, 32);
        union { unsigned u[4]; bf16x8 v; } g0, g1;
        g0.u[0] = h ? pd2 : d0;
        g0.u[1] = h ? pd3 : d1;
        g0.u[2] = h ? d2 : pd0;
        g0.u[3] = h ? d3 : pd1;
        g1.u[0] = h ? pd6 : d4;
        g1.u[1] = h ? pd7 : d5;
        g1.u[2] = h ? d6 : pd4;
        g1.u[3] = h ? d7 : pd5;
        *(bf16x8*)(orow + dt*32 +  0 + h*8) = g0.v;
        *(bf16x8*)(orow + dt*32 + 16 + h*8) = g1.v;
    }
}

// ------------------------------- launch ---------------------------------------
extern "C" void kernel_launch(void* const* d_in, const int* in_sizes, int n_in,
                              void* d_out, int out_size, void* d_ws, size_t ws_size,
                              hipStream_t stream)
{
    const float* x     = (const float*)d_in[0];
    const float* ln1g  = (const float*)d_in[1];
    const float* ln1b  = (const float*)d_in[2];
    const float* qkvw  = (const float*)d_in[3];
    const float* qkvb  = (const float*)d_in[4];
    const float* projw = (const float*)d_in[5];
    const float* projb = (const float*)d_in[6];
    const float* ln2g  = (const float*)d_in[7];
    const float* ln2b  = (const float*)d_in[8];
    const float* fc1w  = (const float*)d_in[9];
    const float* fc1b  = (const float*)d_in[10];
    const float* fc2w  = (const float*)d_in[11];
    const float* fc2b  = (const float*)d_in[12];
    float* out = (float*)d_out;

    char* p = (char*)d_ws;
    auto alloc = [&](size_t bytes) { char* r = p; p += (bytes + 255) & ~(size_t)255; return r; };
    __bf16* wqkvT  = (__bf16*)alloc((size_t)3*CD*CD*2);
    __bf16* wprojT = (__bf16*)alloc((size_t)CD*CD*2);
    __bf16* wfc1T  = (__bf16*)alloc((size_t)HID*CD*2);
    __bf16* wfc2T  = (__bf16*)alloc((size_t)CD*HID*2);
    __bf16* hbuf   = (__bf16*)alloc((size_t)MT*CD*2);
    __bf16* qbuf   = (__bf16*)alloc((size_t)BB*NHD*SEQ*HDD*2);
    __bf16* kbuf   = (__bf16*)alloc((size_t)BB*NHD*SEQ*HDD*2);
    __bf16* vtbuf  = (__bf16*)alloc((size_t)BB*NHD*SEQ*HDD*2);
    (void)alloc((size_t)BB*NHD*SEQ*HDD*2);  // pad so hhbuf (=qbuf) spans 96 MB
    __bf16* hhbuf  = qbuf;                  // reuse for the [MT][3072] MLP act

    prep_kernel<<<1728 + 576 + 2304 + 2304 + MT/4, 256, 0, stream>>>(
        qkvw, projw, fc1w, fc2w, wqkvT, wprojT, wfc1T, wfc2T, x, ln1g, ln1b, hbuf);

    gemm_bt<0><<<(MT/128)*(3*CD/128), 512, 0, stream>>>(
        hbuf, wqkvT, qkvb, nullptr, nullptr, nullptr, qbuf, kbuf, vtbuf, MT, 3*CD, CD);

    attn_kernel<<<BB*NHD*4, 512, 0, stream>>>(qbuf, kbuf, vtbuf, hbuf);

    gemm_bt<1><<<(MT/128)*(CD/128), 512, 0, stream>>>(
        hbuf, wprojT, projb, x, out, nullptr, nullptr, nullptr, nullptr, MT, CD, CD);

    ln_kernel<<<MT/4, 256, 0, stream>>>(out, ln2g, ln2b, hbuf);

    gemm_bt<2><<<(MT/128)*(HID/128), 512, 0, stream>>>(
        hbuf, wfc1T, fc1b, nullptr, nullptr, hhbuf, nullptr, nullptr, nullptr, MT, HID, CD);

    gemm_bt<1><<<(MT/128)*(CD/128), 512, 0, stream>>>(
        hhbuf, wfc2T, fc2b, out, out, nullptr, nullptr, nullptr, nullptr, MT, CD, HID);
}